// Round 4
// baseline (7667.340 us; speedup 1.0000x reference)
//
#include <hip/hip_runtime.h>
#include <hip/hip_bf16.h>
#include <math.h>

#define HID 256
#define BSZ 64
#define TLEN 256
#define INW 64
#define OUTW 32
#define NOISE_STD 0.05f
#define TAU 0.2f

typedef __attribute__((ext_vector_type(8))) short short8;
typedef __attribute__((ext_vector_type(4))) float floatx4;

// ---------------------------------------------------------------------------
// one-time: convert W [j][i][k] fp32 -> bf16, swizzled into MFMA B-fragment
// order. B[k][n=i] fragment for (j, kk, ni): lane l holds 8 elems
//   W[j][ i = ni*16 + (l&15) ][ k = kk*32 + (l>>4)*8 + e ],  e=0..7
// ---------------------------------------------------------------------------
__global__ __launch_bounds__(256) void swizzle_kernel(const float* __restrict__ W,
                                                      __hip_bfloat16* __restrict__ Wsw) {
    int g = blockIdx.x * 256 + threadIdx.x;      // 0 .. 2^21-1
    int l  = g & 63;
    int ni = (g >> 6) & 15;
    int kk = (g >> 10) & 7;
    int j  = g >> 13;
    int i  = ni * 16 + (l & 15);
    int k0 = kk * 32 + (l >> 4) * 8;
    const float* __restrict__ src = W + ((size_t)j * HID + i) * HID + k0;
    __hip_bfloat16* __restrict__ dst = Wsw + (size_t)g * 8;
#pragma unroll
    for (int e = 0; e < 8; ++e) dst[e] = __float2bfloat16(src[e]);
}

// ---------------------------------------------------------------------------
// init: rbf0 = bf16(tanh(x0))
// ---------------------------------------------------------------------------
__global__ __launch_bounds__(256) void init_kernel(const float* __restrict__ x0,
                                                   __hip_bfloat16* __restrict__ rbf) {
    int idx = blockIdx.x * 256 + threadIdx.x;    // 0..16383
    rbf[idx] = __float2bfloat16(tanhf(x0[idx]));
}

// ---------------------------------------------------------------------------
// one-time: pre[t][j][b] = NOISE_STD*noise[t][b][j]
//                        + TAU*(w_in_b[j] + sum_in u[b][t][in]*w_in_w[j][in])
// block = t (256), thread = j (256)
// ---------------------------------------------------------------------------
__global__ __launch_bounds__(256) void pre_kernel(const float* __restrict__ u,
                                                  const float* __restrict__ w_in_w,
                                                  const float* __restrict__ w_in_b,
                                                  const float* __restrict__ noise,
                                                  float* __restrict__ pre) {
    __shared__ float ulds[BSZ][INW + 4];   // padded rows: conflict-free b128 writes
    const int t = blockIdx.x;
    const int j = threadIdx.x;
    {
        int b = threadIdx.x >> 2, q = threadIdx.x & 3;
#pragma unroll
        for (int e = 0; e < 4; ++e) {
            float4 v = *(const float4*)(u + ((size_t)b * TLEN + t) * INW + q * 16 + e * 4);
            *(float4*)&ulds[b][q * 16 + e * 4] = v;
        }
    }
    float wreg[INW];
#pragma unroll
    for (int q = 0; q < INW / 4; ++q) {
        float4 v = *(const float4*)(w_in_w + (size_t)j * INW + q * 4);
        wreg[q * 4 + 0] = v.x; wreg[q * 4 + 1] = v.y;
        wreg[q * 4 + 2] = v.z; wreg[q * 4 + 3] = v.w;
    }
    float bias = w_in_b[j];
    __syncthreads();
    for (int b = 0; b < BSZ; ++b) {
        float s = bias;
#pragma unroll
        for (int in_ = 0; in_ < INW; ++in_) s = fmaf(ulds[b][in_], wreg[in_], s);
        float nz = noise[((size_t)t * BSZ + b) * HID + j];   // coalesced across j
        pre[((size_t)t * HID + j) * BSZ + b] = NOISE_STD * nz + TAU * s;
    }
}

// ---------------------------------------------------------------------------
// persistent kernel: block j (256 blocks = 1 per CU, forced by 132 KB LDS).
// W slice staged to LDS once; 256 timesteps inside. Grid sync = decentralized
// per-producer epoch flags (one cache line each): producer release-stores
// ready[j]=t+1 (parallel, no atomic RMW chain); consumer thread tid polls
// flag tid relaxed, then __syncthreads + threadfence completes the wait.
// ---------------------------------------------------------------------------
__global__ __launch_bounds__(256, 1) void persist_kernel(
    const __hip_bfloat16* __restrict__ Wsw,   // swizzled [j][kk][ni][lane][8]
    const float* __restrict__ w_hh,           // [HID][HID]
    const float* __restrict__ u,              // [B][T][IN]      (fallback)
    const float* __restrict__ w_in_w,         // [HID][IN]       (fallback)
    const float* __restrict__ w_in_b,         // [HID]           (fallback)
    const float* __restrict__ noise,          // [T][B][HID]     (fallback)
    const float* __restrict__ x0,             // [B][HID]
    __hip_bfloat16* __restrict__ rb0,         // [B][HID] bf16 (t even reads)
    __hip_bfloat16* __restrict__ rb1,         // [B][HID] bf16 (t odd reads)
    float* __restrict__ traj,                 // [B][T][HID]
    float* __restrict__ xfinal,               // [B][HID]
    int* __restrict__ ready,                  // [256*16] epoch flags (zeroed)
    const float* __restrict__ pre,            // [T][HID][B] or unused
    int use_pre) {
    __shared__ short Wlds[65536];             // 128 KB: per-j W slice, frag order
    __shared__ float redw[4][64];

    const int tid  = threadIdx.x;
    const int j    = blockIdx.x;
    const int w    = tid >> 6;
    const int lane = tid & 63;
    const int quad = lane >> 4;
    const int col  = lane & 15;

    // ---- stage W slice (once) ----
    {
        const short* __restrict__ src = (const short*)Wsw + (size_t)j * 65536;
#pragma unroll
        for (int m = 0; m < 32; ++m) {
            int i8 = m * 256 + tid;
            *(short8*)&Wlds[i8 * 8] = *(const short8*)&src[(size_t)i8 * 8];
        }
    }
    float xb = 0.f;
    if (tid < BSZ) xb = x0[tid * HID + j];
    __syncthreads();

#pragma unroll 1
    for (int t = 0; t < TLEN; ++t) {
        // ---- wait for all producers of step t-1 (decentralized flags) ----
        if (t > 0) {
            while (__hip_atomic_load(ready + tid * 16, __ATOMIC_RELAXED,
                                     __HIP_MEMORY_SCOPE_AGENT) < t)
                __builtin_amdgcn_s_sleep(1);
            __syncthreads();       // all 256 flags confirmed block-wide
            __threadfence();       // acquire: invalidate stale caches
        }

        const short* __restrict__ cur = (const short*)((t & 1) ? rb1 : rb0);
        __hip_bfloat16* __restrict__ nxt = (t & 1) ? rb0 : rb1;

        // ---- GEMM: P[b,i] = sum_k r[b,k] * W[j,i,k] ----
        floatx4 acc[4][4];
#pragma unroll
        for (int mb = 0; mb < 4; ++mb)
#pragma unroll
            for (int nj = 0; nj < 4; ++nj) acc[mb][nj] = (floatx4){0.f, 0.f, 0.f, 0.f};

#pragma unroll
        for (int kk = 0; kk < 8; ++kk) {
            short8 afrag[4];
#pragma unroll
            for (int mb = 0; mb < 4; ++mb)
                afrag[mb] = *(const short8*)(cur + ((mb * 16 + col) * HID + kk * 32 + quad * 8));
#pragma unroll
            for (int nj = 0; nj < 4; ++nj) {
                short8 bfrag = *(const short8*)&Wlds[((kk * 16 + (w * 4 + nj)) * 64 + lane) * 8];
#pragma unroll
                for (int mb = 0; mb < 4; ++mb)
                    acc[mb][nj] = __builtin_amdgcn_mfma_f32_16x16x32_bf16(
                        afrag[mb], bfrag, acc[mb][nj], 0, 0, 0);
            }
        }

        // ---- epilogue: part[b] = sum_i r[b,i]*(P[b,i] + w_hh[j,i]) ----
        float part[16];
#pragma unroll
        for (int p = 0; p < 16; ++p) part[p] = 0.f;

#pragma unroll
        for (int nj = 0; nj < 4; ++nj) {
            int i = (w * 4 + nj) * 16 + col;
            float whh = w_hh[j * HID + i];
#pragma unroll
            for (int mb = 0; mb < 4; ++mb) {
#pragma unroll
                for (int reg = 0; reg < 4; ++reg) {
                    int b = mb * 16 + quad * 4 + reg;
                    float val = acc[mb][nj][reg] + whh;
                    float rv = __bfloat162float(((const __hip_bfloat16*)cur)[b * HID + i]);
                    part[mb * 4 + reg] = fmaf(rv, val, part[mb * 4 + reg]);
                }
            }
        }
#pragma unroll
        for (int s = 1; s < 16; s <<= 1) {
#pragma unroll
            for (int p = 0; p < 16; ++p) part[p] += __shfl_xor(part[p], s, 64);
        }
        if (col == 0) {
#pragma unroll
            for (int mb = 0; mb < 4; ++mb)
#pragma unroll
                for (int reg = 0; reg < 4; ++reg)
                    redw[w][mb * 16 + quad * 4 + reg] = part[mb * 4 + reg];
        }
        __syncthreads();

        float xn = 0.f;
        if (tid < BSZ) {
            const int b = tid;
            float rec = redw[0][b] + redw[1][b] + redw[2][b] + redw[3][b];

            float extra;
            if (use_pre) {
                extra = pre[((size_t)t * HID + j) * BSZ + b];   // one 256B line
            } else {
                float isum = w_in_b[j];
                const float4* __restrict__ urow =
                    (const float4*)(u + ((size_t)b * TLEN + t) * INW);
                const float4* __restrict__ wrow = (const float4*)(w_in_w + (size_t)j * INW);
#pragma unroll
                for (int q = 0; q < INW / 4; ++q) {
                    float4 uu = urow[q], ww = wrow[q];
                    isum = fmaf(uu.x, ww.x, isum);
                    isum = fmaf(uu.y, ww.y, isum);
                    isum = fmaf(uu.z, ww.z, isum);
                    isum = fmaf(uu.w, ww.w, isum);
                }
                float nz = noise[((size_t)t * BSZ + b) * HID + j];
                extra = NOISE_STD * nz + TAU * isum;
            }
            xn = xb + extra + TAU * (rec - xb);
            if (t < TLEN - 1) nxt[b * HID + j] = __float2bfloat16(tanhf(xn));
        }
        __syncthreads();   // r stores drained (vmcnt(0)) before release

        if (tid == 0 && t < TLEN - 1)
            __hip_atomic_store(ready + j * 16, t + 1, __ATOMIC_RELEASE,
                               __HIP_MEMORY_SCOPE_AGENT);

        if (tid < BSZ) {   // off the inter-block critical path
            const int b = tid;
            traj[((size_t)b * TLEN + t) * HID + j] = xn;
            if (t == TLEN - 1) xfinal[b * HID + j] = xn;
            xb = xn;
        }
    }
}

// ---------------------------------------------------------------------------
// output[b,t,o] = w_out_b[o] + sum_h tanh(traj[b,t,h]) * w_out_w[o,h]
// ---------------------------------------------------------------------------
__global__ __launch_bounds__(256) void output_kernel(
    const float* __restrict__ traj,     // [B][T][HID]
    const float* __restrict__ w_out_w,  // [OUT][HID]
    const float* __restrict__ w_out_b,  // [OUT]
    float* __restrict__ out) {          // [B][T][OUT]
    __shared__ float th[8][HID + 1];
    const int bt0 = blockIdx.x * 8;
    const int tid = threadIdx.x;
#pragma unroll
    for (int m = 0; m < 8; ++m) {
        int idx = m * 256 + tid;
        th[idx >> 8][idx & 255] = tanhf(traj[(size_t)bt0 * HID + idx]);
    }
    __syncthreads();
    const int row = tid >> 5, o = tid & 31;
    const float* __restrict__ wrow = w_out_w + (size_t)o * HID;
    float s = w_out_b[o];
#pragma unroll 8
    for (int h = 0; h < HID; ++h) s = fmaf(th[row][h], wrow[h], s);
    out[(size_t)(bt0 + row) * OUTW + o] = s;
}

// ---------------------------------------------------------------------------
extern "C" void kernel_launch(void* const* d_in, const int* in_sizes, int n_in,
                              void* d_out, int out_size, void* d_ws, size_t ws_size,
                              hipStream_t stream) {
    const float* u       = (const float*)d_in[0];  // [B][T][IN]
    const float* x0      = (const float*)d_in[1];  // [B][HID]
    const float* noise   = (const float*)d_in[2];  // [T][B][HID]
    const float* w_hh    = (const float*)d_in[3];  // [HID][HID]
    const float* W       = (const float*)d_in[4];  // [HID][HID][HID]
    const float* w_in_w  = (const float*)d_in[5];  // [HID][IN]
    const float* w_in_b  = (const float*)d_in[6];  // [HID]
    const float* w_out_w = (const float*)d_in[7];  // [OUT][HID]
    const float* w_out_b = (const float*)d_in[8];  // [OUT]

    float* out    = (float*)d_out;                     // [B][T][OUT]
    float* xfinal = out + (size_t)BSZ * TLEN * OUTW;   // +524288
    float* traj   = xfinal + (size_t)BSZ * HID;        // +16384

    // workspace layout (bytes):
    //   Wsw   : 0          .. 33,554,432   (2^24 bf16)
    //   rbf0  : 33,554,432 .. +32,768
    //   rbf1  : 33,587,200 .. +32,768
    //   ready : 33,619,968 .. +16,384      (256 flags, one 64B line each)
    //   pre   : 33,636,352 .. +16,777,216  (optional, [T][HID][B] fp32)
    char* ws = (char*)d_ws;
    __hip_bfloat16* Wsw  = (__hip_bfloat16*)ws;
    __hip_bfloat16* rbf0 = (__hip_bfloat16*)(ws + 33554432);
    __hip_bfloat16* rbf1 = (__hip_bfloat16*)(ws + 33587200);
    int*            rdy  = (int*)(ws + 33619968);
    float*          pre  = (float*)(ws + 33636352);
    const size_t NEED_PRE = 33636352ull + 16777216ull;
    const int use_pre = (ws_size >= NEED_PRE) ? 1 : 0;

    hipMemsetAsync(rdy, 0, 16384, stream);
    swizzle_kernel<<<8192, 256, 0, stream>>>(W, Wsw);
    init_kernel<<<64, 256, 0, stream>>>(x0, rbf0);
    if (use_pre)
        pre_kernel<<<TLEN, 256, 0, stream>>>(u, w_in_w, w_in_b, noise, pre);

    persist_kernel<<<256, 256, 0, stream>>>(
        Wsw, w_hh, u, w_in_w, w_in_b, noise, x0,
        rbf0, rbf1, traj, xfinal, rdy, pre, use_pre);

    output_kernel<<<(BSZ * TLEN) / 8, 256, 0, stream>>>(traj, w_out_w, w_out_b, out);
}

// Round 5
// 2459.984 us; speedup vs baseline: 3.1168x; 3.1168x over previous
//
#include <hip/hip_runtime.h>
#include <hip/hip_bf16.h>
#include <math.h>

#define HID 256
#define BSZ 64
#define TLEN 256
#define INW 64
#define OUTW 32
#define NOISE_STD 0.05f
#define TAU 0.2f

typedef __attribute__((ext_vector_type(8))) short short8;
typedef __attribute__((ext_vector_type(4))) float floatx4;
typedef unsigned long long u64;

// ---------------------------------------------------------------------------
// one-time: convert W [j][i][k] fp32 -> bf16, swizzled into MFMA B-fragment
// order. B[k][n=i] fragment for (j, kk, ni): lane l holds 8 elems
//   W[j][ i = ni*16 + (l&15) ][ k = kk*32 + (l>>4)*8 + e ],  e=0..7
// ---------------------------------------------------------------------------
__global__ __launch_bounds__(256) void swizzle_kernel(const float* __restrict__ W,
                                                      __hip_bfloat16* __restrict__ Wsw) {
    int g = blockIdx.x * 256 + threadIdx.x;      // 0 .. 2^21-1
    int l  = g & 63;
    int ni = (g >> 6) & 15;
    int kk = (g >> 10) & 7;
    int j  = g >> 13;
    int i  = ni * 16 + (l & 15);
    int k0 = kk * 32 + (l >> 4) * 8;
    const float* __restrict__ src = W + ((size_t)j * HID + i) * HID + k0;
    __hip_bfloat16* __restrict__ dst = Wsw + (size_t)g * 8;
#pragma unroll
    for (int e = 0; e < 8; ++e) dst[e] = __float2bfloat16(src[e]);
}

// ---------------------------------------------------------------------------
// init: rT0[k][b] = bf16(tanh(x0[b][k]))   (transposed state layout)
// ---------------------------------------------------------------------------
__global__ __launch_bounds__(256) void init_kernel(const float* __restrict__ x0,
                                                   __hip_bfloat16* __restrict__ rT0) {
    int idx = blockIdx.x * 256 + threadIdx.x;    // 0..16383
    int b = idx >> 8, k = idx & 255;
    rT0[k * BSZ + b] = __float2bfloat16(tanhf(x0[idx]));
}

// ---------------------------------------------------------------------------
// one-time: pre[t][j][b] = NOISE_STD*noise[t][b][j]
//                        + TAU*(w_in_b[j] + sum_in u[b][t][in]*w_in_w[j][in])
// ---------------------------------------------------------------------------
__global__ __launch_bounds__(256) void pre_kernel(const float* __restrict__ u,
                                                  const float* __restrict__ w_in_w,
                                                  const float* __restrict__ w_in_b,
                                                  const float* __restrict__ noise,
                                                  float* __restrict__ pre) {
    __shared__ float ulds[BSZ][INW + 4];
    const int t = blockIdx.x;
    const int j = threadIdx.x;
    {
        int b = threadIdx.x >> 2, q = threadIdx.x & 3;
#pragma unroll
        for (int e = 0; e < 4; ++e) {
            float4 v = *(const float4*)(u + ((size_t)b * TLEN + t) * INW + q * 16 + e * 4);
            *(float4*)&ulds[b][q * 16 + e * 4] = v;
        }
    }
    float wreg[INW];
#pragma unroll
    for (int q = 0; q < INW / 4; ++q) {
        float4 v = *(const float4*)(w_in_w + (size_t)j * INW + q * 4);
        wreg[q * 4 + 0] = v.x; wreg[q * 4 + 1] = v.y;
        wreg[q * 4 + 2] = v.z; wreg[q * 4 + 3] = v.w;
    }
    float bias = w_in_b[j];
    __syncthreads();
    for (int b = 0; b < BSZ; ++b) {
        float s = bias;
#pragma unroll
        for (int in_ = 0; in_ < INW; ++in_) s = fmaf(ulds[b][in_], wreg[in_], s);
        float nz = noise[((size_t)t * BSZ + b) * HID + j];
        pre[((size_t)t * HID + j) * BSZ + b] = NOISE_STD * nz + TAU * s;
    }
}

// ---------------------------------------------------------------------------
// persistent kernel, coherence-light protocol:
//  - state rT[k][b] bf16 in global, double-buffered; ALL cross-block traffic
//    (rT + flags) via agent-scope relaxed atomics -> L1/L2 bypassed, MALL is
//    the coherence point. NO threadfence / wbl2 / buffer_inv in the loop.
//  - producer j: 16x8B coalesced atomic stores of its r column, raw
//    s_waitcnt vmcnt(0), relaxed flag store ready[j]=t+1.
//  - consumer: per-thread flag poll + syncthreads, then re-stage rT into LDS
//    (XOR-swizzled transpose; no padding). LDS = 128K W + 32K r = exactly 160K;
//    redw/exch alias the r tile between barriers.
// ---------------------------------------------------------------------------
__global__ __launch_bounds__(256, 1) void persist_kernel(
    const __hip_bfloat16* __restrict__ Wsw,   // swizzled [j][kk][ni][lane][8]
    const float* __restrict__ w_hh,           // [HID][HID]
    const float* __restrict__ u,              // [B][T][IN]   (fallback)
    const float* __restrict__ w_in_w,         // [HID][IN]    (fallback)
    const float* __restrict__ w_in_b,         // [HID]        (fallback)
    const float* __restrict__ noise,          // [T][B][HID]  (fallback)
    const float* __restrict__ x0,             // [B][HID]
    u64* __restrict__ rT0,                    // [HID][BSZ] bf16 as 4096 u64
    u64* __restrict__ rT1,
    float* __restrict__ traj,                 // [B][T][HID]
    float* __restrict__ xfinal,               // [B][HID]
    int* __restrict__ ready,                  // 256 flags, 64B apart (zeroed)
    const float* __restrict__ pre,            // [T][HID][B] or unused
    int use_pre) {
    __shared__ short Wlds[65536];             // 128 KB
    __shared__ short rlds[16384];             // 32 KB: rlds[b*256 + (k^swz(b))]

    const int tid  = threadIdx.x;
    const int j    = blockIdx.x;
    const int w    = tid >> 6;
    const int lane = tid & 63;
    const int quad = lane >> 4;
    const int col  = lane & 15;

    float* redw = (float*)rlds;                              // [4][64], aliased
    __hip_bfloat16* exch = (__hip_bfloat16*)(rlds + 512);    // 64 bf16, aliased
    u64* exchU = (u64*)(rlds + 512);

    // ---- stage W slice (once) ----
    {
        const short* __restrict__ src = (const short*)Wsw + (size_t)j * 65536;
#pragma unroll
        for (int m = 0; m < 32; ++m) {
            int i8 = m * 256 + tid;
            *(short8*)&Wlds[i8 * 8] = *(const short8*)&src[(size_t)i8 * 8];
        }
    }
    // ---- per-lane loop-invariant preloads ----
    float whh_reg[4];
#pragma unroll
    for (int nj = 0; nj < 4; ++nj)
        whh_reg[nj] = w_hh[j * HID + (w * 4 + nj) * 16 + col];

    float xb = 0.f;
    if (tid < BSZ) xb = x0[tid * HID + j];
    __syncthreads();

    const int fill_k = (tid >> 4);        // + c*16
    const int fill_b0 = (tid & 15) * 4;

#pragma unroll 1
    for (int t = 0; t < TLEN; ++t) {
        // ---- wait for step t-1 producers (relaxed sc-load poll, no fence) ----
        if (t > 0) {
            while (__hip_atomic_load(ready + tid * 16, __ATOMIC_RELAXED,
                                     __HIP_MEMORY_SCOPE_AGENT) < t)
                __builtin_amdgcn_s_sleep(1);
            asm volatile("" ::: "memory");
            __syncthreads();
        }

        const u64* __restrict__ rcur = (t & 1) ? rT1 : rT0;
        u64* __restrict__ rnxt = (t & 1) ? rT0 : rT1;

        // ---- early prefetch of the input term (hides under fill+GEMM) ----
        float extra = 0.f;
        if (tid < BSZ) {
            if (use_pre) {
                extra = pre[((size_t)t * HID + j) * BSZ + tid];
            } else {
                float isum = w_in_b[j];
                const float4* __restrict__ urow =
                    (const float4*)(u + ((size_t)tid * TLEN + t) * INW);
                const float4* __restrict__ wrow = (const float4*)(w_in_w + (size_t)j * INW);
#pragma unroll
                for (int q = 0; q < INW / 4; ++q) {
                    float4 uu = urow[q], ww = wrow[q];
                    isum = fmaf(uu.x, ww.x, isum);
                    isum = fmaf(uu.y, ww.y, isum);
                    isum = fmaf(uu.z, ww.z, isum);
                    isum = fmaf(uu.w, ww.w, isum);
                }
                float nz = noise[((size_t)t * BSZ + tid) * HID + j];
                extra = NOISE_STD * nz + TAU * isum;
            }
        }

        // ---- fill rlds: coalesced sc-loads + swizzled transpose ----
        {
            u64 v[16];
#pragma unroll
            for (int c = 0; c < 16; ++c)
                v[c] = __hip_atomic_load(rcur + c * 256 + tid, __ATOMIC_RELAXED,
                                         __HIP_MEMORY_SCOPE_AGENT);
#pragma unroll
            for (int c = 0; c < 16; ++c) {
                int k = c * 16 + fill_k;
#pragma unroll
                for (int i2 = 0; i2 < 4; ++i2) {
                    int b = fill_b0 + i2;
                    rlds[b * 256 + (k ^ ((b & 31) << 3))] = (short)(v[c] >> (16 * i2));
                }
            }
        }
        __syncthreads();

        // ---- GEMM: P[b,i] = sum_k r[b,k] * W[j,i,k] ----
        floatx4 acc[4][4];
#pragma unroll
        for (int mb = 0; mb < 4; ++mb)
#pragma unroll
            for (int nj = 0; nj < 4; ++nj) acc[mb][nj] = (floatx4){0.f, 0.f, 0.f, 0.f};

#pragma unroll
        for (int kk = 0; kk < 8; ++kk) {
            short8 afrag[4];
#pragma unroll
            for (int mb = 0; mb < 4; ++mb) {
                int b = mb * 16 + col;
                int k0 = kk * 32 + quad * 8;
                afrag[mb] = *(const short8*)&rlds[b * 256 + (k0 ^ ((b & 31) << 3))];
            }
#pragma unroll
            for (int nj = 0; nj < 4; ++nj) {
                short8 bfrag = *(const short8*)&Wlds[((kk * 16 + (w * 4 + nj)) * 64 + lane) * 8];
#pragma unroll
                for (int mb = 0; mb < 4; ++mb)
                    acc[mb][nj] = __builtin_amdgcn_mfma_f32_16x16x32_bf16(
                        afrag[mb], bfrag, acc[mb][nj], 0, 0, 0);
            }
        }

        // ---- epilogue: part[b] = sum_i r[b,i]*(P[b,i] + w_hh[j,i]) ----
        float part[16];
#pragma unroll
        for (int p = 0; p < 16; ++p) part[p] = 0.f;

#pragma unroll
        for (int nj = 0; nj < 4; ++nj) {
            int i = (w * 4 + nj) * 16 + col;
            float whh = whh_reg[nj];
#pragma unroll
            for (int mb = 0; mb < 4; ++mb) {
#pragma unroll
                for (int reg = 0; reg < 4; ++reg) {
                    int b = mb * 16 + quad * 4 + reg;
                    short rs = rlds[b * 256 + (i ^ ((b & 31) << 3))];
                    float rv = __bfloat162float(*(__hip_bfloat16*)&rs);
                    part[mb * 4 + reg] = fmaf(rv, acc[mb][nj][reg] + whh, part[mb * 4 + reg]);
                }
            }
        }
#pragma unroll
        for (int s = 1; s < 16; s <<= 1) {
#pragma unroll
            for (int p = 0; p < 16; ++p) part[p] += __shfl_xor(part[p], s, 64);
        }
        __syncthreads();          // all rlds reads done (redw aliases rlds)
        if (col == 0) {
#pragma unroll
            for (int mb = 0; mb < 4; ++mb)
#pragma unroll
                for (int reg = 0; reg < 4; ++reg)
                    redw[w * 64 + mb * 16 + quad * 4 + reg] = part[mb * 4 + reg];
        }
        __syncthreads();

        float xn = 0.f;
        if (tid < BSZ) {
            const int b = tid;
            float rec = redw[b] + redw[64 + b] + redw[128 + b] + redw[192 + b];
            xn = xb + extra + TAU * (rec - xb);
            xb = xn;
            if (t < TLEN - 1) exch[b] = __float2bfloat16(tanhf(xn));  // wave-0 LDS
        }

        if (t < TLEN - 1) {
            if (tid < 16) {       // wave 0: 16x8B coalesced sc-stores of column j
                u64 pv = exchU[tid];
                __hip_atomic_store(rnxt + j * 16 + tid, pv, __ATOMIC_RELAXED,
                                   __HIP_MEMORY_SCOPE_AGENT);
            }
            if (tid < 64)         // wave 0 only: drain own stores (no wbl2!)
                asm volatile("s_waitcnt vmcnt(0)" ::: "memory");
            if (tid == 0)
                __hip_atomic_store(ready + j * 16, t + 1, __ATOMIC_RELAXED,
                                   __HIP_MEMORY_SCOPE_AGENT);
        }

        if (tid < BSZ) {          // off the critical path
            traj[((size_t)tid * TLEN + t) * HID + j] = xn;
            if (t == TLEN - 1) xfinal[tid * HID + j] = xn;
        }
    }
}

// ---------------------------------------------------------------------------
// output[b,t,o] = w_out_b[o] + sum_h tanh(traj[b,t,h]) * w_out_w[o,h]
// ---------------------------------------------------------------------------
__global__ __launch_bounds__(256) void output_kernel(
    const float* __restrict__ traj,     // [B][T][HID]
    const float* __restrict__ w_out_w,  // [OUT][HID]
    const float* __restrict__ w_out_b,  // [OUT]
    float* __restrict__ out) {          // [B][T][OUT]
    __shared__ float th[8][HID + 1];
    const int bt0 = blockIdx.x * 8;
    const int tid = threadIdx.x;
#pragma unroll
    for (int m = 0; m < 8; ++m) {
        int idx = m * 256 + tid;
        th[idx >> 8][idx & 255] = tanhf(traj[(size_t)bt0 * HID + idx]);
    }
    __syncthreads();
    const int row = tid >> 5, o = tid & 31;
    const float* __restrict__ wrow = w_out_w + (size_t)o * HID;
    float s = w_out_b[o];
#pragma unroll 8
    for (int h = 0; h < HID; ++h) s = fmaf(th[row][h], wrow[h], s);
    out[(size_t)(bt0 + row) * OUTW + o] = s;
}

// ---------------------------------------------------------------------------
extern "C" void kernel_launch(void* const* d_in, const int* in_sizes, int n_in,
                              void* d_out, int out_size, void* d_ws, size_t ws_size,
                              hipStream_t stream) {
    const float* u       = (const float*)d_in[0];  // [B][T][IN]
    const float* x0      = (const float*)d_in[1];  // [B][HID]
    const float* noise   = (const float*)d_in[2];  // [T][B][HID]
    const float* w_hh    = (const float*)d_in[3];  // [HID][HID]
    const float* W       = (const float*)d_in[4];  // [HID][HID][HID]
    const float* w_in_w  = (const float*)d_in[5];  // [HID][IN]
    const float* w_in_b  = (const float*)d_in[6];  // [HID]
    const float* w_out_w = (const float*)d_in[7];  // [OUT][HID]
    const float* w_out_b = (const float*)d_in[8];  // [OUT]

    float* out    = (float*)d_out;                     // [B][T][OUT]
    float* xfinal = out + (size_t)BSZ * TLEN * OUTW;   // +524288
    float* traj   = xfinal + (size_t)BSZ * HID;        // +16384

    // workspace layout (bytes):
    //   Wsw   : 0          .. 33,554,432   (2^24 bf16)
    //   rT0   : 33,554,432 .. +32,768      ([HID][BSZ] bf16)
    //   rT1   : 33,587,200 .. +32,768
    //   ready : 33,619,968 .. +16,384      (256 flags, one 64B line each)
    //   pre   : 33,636,352 .. +16,777,216  (optional, [T][HID][B] fp32)
    char* ws = (char*)d_ws;
    __hip_bfloat16* Wsw = (__hip_bfloat16*)ws;
    u64*   rT0 = (u64*)(ws + 33554432);
    u64*   rT1 = (u64*)(ws + 33587200);
    int*   rdy = (int*)(ws + 33619968);
    float* pre = (float*)(ws + 33636352);
    const size_t NEED_PRE = 33636352ull + 16777216ull;
    const int use_pre = (ws_size >= NEED_PRE) ? 1 : 0;

    hipMemsetAsync(rdy, 0, 16384, stream);
    swizzle_kernel<<<8192, 256, 0, stream>>>(W, Wsw);
    init_kernel<<<64, 256, 0, stream>>>(x0, (__hip_bfloat16*)rT0);
    if (use_pre)
        pre_kernel<<<TLEN, 256, 0, stream>>>(u, w_in_w, w_in_b, noise, pre);

    persist_kernel<<<256, 256, 0, stream>>>(
        Wsw, w_hh, u, w_in_w, w_in_b, noise, x0,
        rT0, rT1, traj, xfinal, rdy, pre, use_pre);

    output_kernel<<<(BSZ * TLEN) / 8, 256, 0, stream>>>(traj, w_out_w, w_out_b, out);
}

// Round 6
// 1759.074 us; speedup vs baseline: 4.3587x; 1.3985x over previous
//
#include <hip/hip_runtime.h>
#include <hip/hip_bf16.h>
#include <math.h>

#define HID 256
#define BSZ 64
#define TLEN 256
#define INW 64
#define OUTW 32
#define NOISE_STD 0.05f
#define TAU 0.2f

typedef __attribute__((ext_vector_type(8))) short short8;
typedef __attribute__((ext_vector_type(4))) float floatx4;
typedef unsigned long long u64;

// LDS layout for r: [b][k] with 8-short-granule XOR swizzle.
// ridx(b,k) = b*256 + ((k>>3) ^ ((b>>2)&7) ^ ((b&3)<<1))*8 + (k&7)
// Derived (bank = dword%32): fill 2B writes <=2-way; A-frag ds_read_b128
// uniform 8 lanes per 4-bank group (optimal); epilogue scalar <=2-way.
__device__ __forceinline__ int ridx(int b, int k) {
    int P = ((b >> 2) & 7) ^ ((b & 3) << 1);
    return b * 256 + ((((k >> 3) ^ P) & 31) << 3) + (k & 7);
}

// ---------------------------------------------------------------------------
// one-time: W [j][i][k] fp32 -> bf16 in MFMA B-fragment order
//   Wsw[(((j*8+kk)*16+ni)*64+l)*8 + e] = W[j][ni*16+(l&15)][kk*32+(l>>4)*8+e]
// ---------------------------------------------------------------------------
__global__ __launch_bounds__(256) void swizzle_kernel(const float* __restrict__ W,
                                                      __hip_bfloat16* __restrict__ Wsw) {
    int g = blockIdx.x * 256 + threadIdx.x;      // 0 .. 2^21-1
    int l  = g & 63;
    int ni = (g >> 6) & 15;
    int kk = (g >> 10) & 7;
    int j  = g >> 13;
    int i  = ni * 16 + (l & 15);
    int k0 = kk * 32 + (l >> 4) * 8;
    const float* __restrict__ src = W + ((size_t)j * HID + i) * HID + k0;
    __hip_bfloat16* __restrict__ dst = Wsw + (size_t)g * 8;
#pragma unroll
    for (int e = 0; e < 8; ++e) dst[e] = __float2bfloat16(src[e]);
}

// ---------------------------------------------------------------------------
// init: rT0[k][b] = bf16(tanh(x0[b][k]))
// ---------------------------------------------------------------------------
__global__ __launch_bounds__(256) void init_kernel(const float* __restrict__ x0,
                                                   __hip_bfloat16* __restrict__ rT0) {
    int idx = blockIdx.x * 256 + threadIdx.x;    // 0..16383
    int b = idx >> 8, k = idx & 255;
    rT0[k * BSZ + b] = __float2bfloat16(tanhf(x0[idx]));
}

// ---------------------------------------------------------------------------
// one-time: pre[t][j][b] = NOISE_STD*noise[t][b][j]
//                        + TAU*(w_in_b[j] + sum_in u[b][t][in]*w_in_w[j][in])
// ---------------------------------------------------------------------------
__global__ __launch_bounds__(256) void pre_kernel(const float* __restrict__ u,
                                                  const float* __restrict__ w_in_w,
                                                  const float* __restrict__ w_in_b,
                                                  const float* __restrict__ noise,
                                                  float* __restrict__ pre) {
    __shared__ float ulds[BSZ][INW + 4];
    const int t = blockIdx.x;
    const int j = threadIdx.x;
    {
        int b = threadIdx.x >> 2, q = threadIdx.x & 3;
#pragma unroll
        for (int e = 0; e < 4; ++e) {
            float4 v = *(const float4*)(u + ((size_t)b * TLEN + t) * INW + q * 16 + e * 4);
            *(float4*)&ulds[b][q * 16 + e * 4] = v;
        }
    }
    float wreg[INW];
#pragma unroll
    for (int q = 0; q < INW / 4; ++q) {
        float4 v = *(const float4*)(w_in_w + (size_t)j * INW + q * 4);
        wreg[q * 4 + 0] = v.x; wreg[q * 4 + 1] = v.y;
        wreg[q * 4 + 2] = v.z; wreg[q * 4 + 3] = v.w;
    }
    float bias = w_in_b[j];
    __syncthreads();
    for (int b = 0; b < BSZ; ++b) {
        float s = bias;
#pragma unroll
        for (int in_ = 0; in_ < INW; ++in_) s = fmaf(ulds[b][in_], wreg[in_], s);
        float nz = noise[((size_t)t * BSZ + b) * HID + j];
        pre[((size_t)t * HID + j) * BSZ + b] = NOISE_STD * nz + TAU * s;
    }
}

// ---------------------------------------------------------------------------
// persistent kernel (R5 protocol, fixed LDS swizzle + coalesced traj):
//  - cross-block traffic (rT + flags) via agent-scope relaxed atomics (MALL)
//  - producer: 16x8B data stores -> s_waitcnt vmcnt(0) -> flag store
//  - consumer: per-thread flag poll -> coalesced 8B loads -> swizzled LDS
//  - traj: one coalesced 256B store per step into trajWS[t][j][b]
// ---------------------------------------------------------------------------
__global__ __launch_bounds__(256, 1) void persist_kernel(
    const __hip_bfloat16* __restrict__ Wsw,
    const float* __restrict__ w_hh,
    const float* __restrict__ u,              // fallbacks
    const float* __restrict__ w_in_w,
    const float* __restrict__ w_in_b,
    const float* __restrict__ noise,
    const float* __restrict__ x0,
    u64* __restrict__ rT0,                    // [HID][BSZ] bf16 as 4096 u64
    u64* __restrict__ rT1,
    float* __restrict__ traj,                 // [B][T][HID] (fallback path)
    float* __restrict__ trajWS,               // [T][HID][B] (fast path)
    float* __restrict__ xfinal,
    int* __restrict__ ready,                  // 256 flags, 64B apart (zeroed)
    const float* __restrict__ pre,            // [T][HID][B] or unused
    int use_pre, int use_tws) {
    __shared__ short Wlds[65536];             // 128 KB
    __shared__ short rlds[16384];             // 32 KB, swizzled [b][k]

    const int tid  = threadIdx.x;
    const int j    = blockIdx.x;
    const int w    = tid >> 6;
    const int lane = tid & 63;
    const int quad = lane >> 4;
    const int col  = lane & 15;

    float* redw = (float*)rlds;                              // [4][64], aliased
    __hip_bfloat16* exch = (__hip_bfloat16*)(rlds + 512);    // 64 bf16, aliased
    u64* exchU = (u64*)(rlds + 512);

    // ---- stage W slice (once) ----
    {
        const short* __restrict__ src = (const short*)Wsw + (size_t)j * 65536;
#pragma unroll
        for (int m = 0; m < 32; ++m) {
            int i8 = m * 256 + tid;
            *(short8*)&Wlds[i8 * 8] = *(const short8*)&src[(size_t)i8 * 8];
        }
    }
    float whh_reg[4];
#pragma unroll
    for (int nj = 0; nj < 4; ++nj)
        whh_reg[nj] = w_hh[j * HID + (w * 4 + nj) * 16 + col];

    float xb = 0.f;
    if (tid < BSZ) xb = x0[tid * HID + j];
    __syncthreads();

    const int fill_k = tid >> 4;     // + c*16
    const int fill_b0 = (tid & 15) * 4;

#pragma unroll 1
    for (int t = 0; t < TLEN; ++t) {
        if (t > 0) {
            while (__hip_atomic_load(ready + tid * 16, __ATOMIC_RELAXED,
                                     __HIP_MEMORY_SCOPE_AGENT) < t)
                __builtin_amdgcn_s_sleep(1);
            asm volatile("" ::: "memory");
            __syncthreads();
        }

        const u64* __restrict__ rcur = (t & 1) ? rT1 : rT0;
        u64* __restrict__ rnxt = (t & 1) ? rT0 : rT1;

        // ---- input term prefetch ----
        float extra = 0.f;
        if (tid < BSZ) {
            if (use_pre) {
                extra = pre[((size_t)t * HID + j) * BSZ + tid];
            } else {
                float isum = w_in_b[j];
                const float4* __restrict__ urow =
                    (const float4*)(u + ((size_t)tid * TLEN + t) * INW);
                const float4* __restrict__ wrow = (const float4*)(w_in_w + (size_t)j * INW);
#pragma unroll
                for (int q = 0; q < INW / 4; ++q) {
                    float4 uu = urow[q], ww = wrow[q];
                    isum = fmaf(uu.x, ww.x, isum);
                    isum = fmaf(uu.y, ww.y, isum);
                    isum = fmaf(uu.z, ww.z, isum);
                    isum = fmaf(uu.w, ww.w, isum);
                }
                float nz = noise[((size_t)t * BSZ + tid) * HID + j];
                extra = NOISE_STD * nz + TAU * isum;
            }
        }

        // ---- fill rlds: coalesced sc-loads + swizzled transpose ----
        {
            u64 v[16];
#pragma unroll
            for (int c = 0; c < 16; ++c)
                v[c] = __hip_atomic_load(rcur + c * 256 + tid, __ATOMIC_RELAXED,
                                         __HIP_MEMORY_SCOPE_AGENT);
#pragma unroll
            for (int c = 0; c < 16; ++c) {
                int k = c * 16 + fill_k;
#pragma unroll
                for (int i2 = 0; i2 < 4; ++i2)
                    rlds[ridx(fill_b0 + i2, k)] = (short)(v[c] >> (16 * i2));
            }
        }
        __syncthreads();

        // ---- GEMM: P[b,i] = sum_k r[b,k] * W[j,i,k] ----
        floatx4 acc[4][4];
#pragma unroll
        for (int mb = 0; mb < 4; ++mb)
#pragma unroll
            for (int nj = 0; nj < 4; ++nj) acc[mb][nj] = (floatx4){0.f, 0.f, 0.f, 0.f};

#pragma unroll
        for (int kk = 0; kk < 8; ++kk) {
            short8 afrag[4];
#pragma unroll
            for (int mb = 0; mb < 4; ++mb)
                afrag[mb] = *(const short8*)&rlds[ridx(mb * 16 + col, kk * 32 + quad * 8)];
#pragma unroll
            for (int nj = 0; nj < 4; ++nj) {
                short8 bfrag = *(const short8*)&Wlds[((kk * 16 + (w * 4 + nj)) * 64 + lane) * 8];
#pragma unroll
                for (int mb = 0; mb < 4; ++mb)
                    acc[mb][nj] = __builtin_amdgcn_mfma_f32_16x16x32_bf16(
                        afrag[mb], bfrag, acc[mb][nj], 0, 0, 0);
            }
        }

        // ---- epilogue: part[b] = sum_i r[b,i]*(P[b,i] + w_hh[j,i]) ----
        float part[16];
#pragma unroll
        for (int p = 0; p < 16; ++p) part[p] = 0.f;

#pragma unroll
        for (int nj = 0; nj < 4; ++nj) {
            int i = (w * 4 + nj) * 16 + col;
            float whh = whh_reg[nj];
#pragma unroll
            for (int mb = 0; mb < 4; ++mb) {
#pragma unroll
                for (int reg = 0; reg < 4; ++reg) {
                    int b = mb * 16 + quad * 4 + reg;
                    short rs = rlds[ridx(b, i)];
                    float rv = __bfloat162float(*(__hip_bfloat16*)&rs);
                    part[mb * 4 + reg] = fmaf(rv, acc[mb][nj][reg] + whh, part[mb * 4 + reg]);
                }
            }
        }
#pragma unroll
        for (int s = 1; s < 16; s <<= 1) {
#pragma unroll
            for (int p = 0; p < 16; ++p) part[p] += __shfl_xor(part[p], s, 64);
        }
        __syncthreads();          // rlds reads done (redw/exch alias rlds)
        if (col == 0) {
#pragma unroll
            for (int mb = 0; mb < 4; ++mb)
#pragma unroll
                for (int reg = 0; reg < 4; ++reg)
                    redw[w * 64 + mb * 16 + quad * 4 + reg] = part[mb * 4 + reg];
        }
        __syncthreads();

        float xn = 0.f;
        if (tid < BSZ) {
            const int b = tid;
            float rec = redw[b] + redw[64 + b] + redw[128 + b] + redw[192 + b];
            xn = xb + extra + TAU * (rec - xb);
            xb = xn;
            if (use_tws) trajWS[((size_t)t * HID + j) * BSZ + b] = xn;  // 256B coalesced
            if (t < TLEN - 1) exch[b] = __float2bfloat16(tanhf(xn));
        }

        if (t < TLEN - 1) {
            if (tid < 16) {       // wave 0: 16x8B coalesced sc-stores of column j
                u64 pv = exchU[tid];
                __hip_atomic_store(rnxt + j * 16 + tid, pv, __ATOMIC_RELAXED,
                                   __HIP_MEMORY_SCOPE_AGENT);
            }
            if (tid < 64)
                asm volatile("s_waitcnt vmcnt(0)" ::: "memory");
            if (tid == 0)
                __hip_atomic_store(ready + j * 16, t + 1, __ATOMIC_RELAXED,
                                   __HIP_MEMORY_SCOPE_AGENT);
        }

        if (!use_tws && tid < BSZ) {      // fallback scatter path (off crit path)
            traj[((size_t)tid * TLEN + t) * HID + j] = xn;
            if (t == TLEN - 1) xfinal[tid * HID + j] = xn;
        }
        if (use_tws && t == TLEN - 1 && tid < BSZ) {
            // xfinal handled by fixup kernel; nothing to do
        }
    }
}

// ---------------------------------------------------------------------------
// fused transpose + output (fast path). block = t.
// reads trajWS[t][j][b]; writes traj[b][t][:], xfinal (t=255), out[b][t][:]
// ---------------------------------------------------------------------------
__global__ __launch_bounds__(256) void fixup_kernel(
    const float* __restrict__ trajWS,   // [T][HID][B]
    const float* __restrict__ w_out_w,  // [OUT][HID]
    const float* __restrict__ w_out_b,  // [OUT]
    float* __restrict__ traj,           // [B][T][HID]
    float* __restrict__ xfinal,         // [B][HID]
    float* __restrict__ out) {          // [B][T][OUT]
    __shared__ float xv[BSZ * 257];     // [b][j], pad 257: <=2-way everywhere
    __shared__ float wol[OUTW * 257];   // [o][h], pad 257
    const int t = blockIdx.x, tid = threadIdx.x;

#pragma unroll
    for (int it = 0; it < 16; ++it) {
        int flat = it * 1024 + tid * 4;          // j*64 + b
        float4 v = *(const float4*)(trajWS + (size_t)t * 16384 + flat);
        int jj = flat >> 6, b = flat & 63;
        xv[(b + 0) * 257 + jj] = v.x;
        xv[(b + 1) * 257 + jj] = v.y;
        xv[(b + 2) * 257 + jj] = v.z;
        xv[(b + 3) * 257 + jj] = v.w;
    }
#pragma unroll
    for (int it = 0; it < 8; ++it) {
        int flat = it * 1024 + tid * 4;          // o*256 + h
        float4 v = *(const float4*)(w_out_w + flat);
        int o = flat >> 8, h = flat & 255;
        *(float4*)&wol[o * 257 + h] = v;
    }
    __syncthreads();

    for (int b = 0; b < BSZ; ++b)
        traj[((size_t)b * TLEN + t) * HID + tid] = xv[b * 257 + tid];
    if (t == TLEN - 1)
        for (int b = 0; b < BSZ; ++b)
            xfinal[b * HID + tid] = xv[b * 257 + tid];

    __syncthreads();
#pragma unroll
    for (int it = 0; it < 64; ++it) {           // tanh in place
        int b = it;
        xv[b * 257 + tid] = tanhf(xv[b * 257 + tid]);
    }
    __syncthreads();

    const int o = tid & 31;
    const float bias = w_out_b[o];
#pragma unroll 1
    for (int rep = 0; rep < 8; ++rep) {
        int b = rep * 8 + (tid >> 5);
        float s = bias;
#pragma unroll 8
        for (int h = 0; h < HID; ++h)
            s = fmaf(xv[b * 257 + h], wol[o * 257 + h], s);
        out[((size_t)b * TLEN + t) * OUTW + o] = s;
    }
}

// ---------------------------------------------------------------------------
// fallback output kernel (reads traj from d_out) — used when ws too small
// ---------------------------------------------------------------------------
__global__ __launch_bounds__(256) void output_kernel(
    const float* __restrict__ traj, const float* __restrict__ w_out_w,
    const float* __restrict__ w_out_b, float* __restrict__ out) {
    __shared__ float th[8][HID + 1];
    const int bt0 = blockIdx.x * 8;
    const int tid = threadIdx.x;
#pragma unroll
    for (int m = 0; m < 8; ++m) {
        int idx = m * 256 + tid;
        th[idx >> 8][idx & 255] = tanhf(traj[(size_t)bt0 * HID + idx]);
    }
    __syncthreads();
    const int row = tid >> 5, o = tid & 31;
    const float* __restrict__ wrow = w_out_w + (size_t)o * HID;
    float s = w_out_b[o];
#pragma unroll 8
    for (int h = 0; h < HID; ++h) s = fmaf(th[row][h], wrow[h], s);
    out[(size_t)(bt0 + row) * OUTW + o] = s;
}

// ---------------------------------------------------------------------------
extern "C" void kernel_launch(void* const* d_in, const int* in_sizes, int n_in,
                              void* d_out, int out_size, void* d_ws, size_t ws_size,
                              hipStream_t stream) {
    const float* u       = (const float*)d_in[0];
    const float* x0      = (const float*)d_in[1];
    const float* noise   = (const float*)d_in[2];
    const float* w_hh    = (const float*)d_in[3];
    const float* W       = (const float*)d_in[4];
    const float* w_in_w  = (const float*)d_in[5];
    const float* w_in_b  = (const float*)d_in[6];
    const float* w_out_w = (const float*)d_in[7];
    const float* w_out_b = (const float*)d_in[8];

    float* out    = (float*)d_out;                     // [B][T][OUT]
    float* xfinal = out + (size_t)BSZ * TLEN * OUTW;
    float* traj   = xfinal + (size_t)BSZ * HID;

    // ws layout: Wsw 33.5M | rT0 32K | rT1 32K | flags 16K | trajWS 16.7M | pre 16.7M
    char* ws = (char*)d_ws;
    __hip_bfloat16* Wsw = (__hip_bfloat16*)ws;
    u64*   rT0 = (u64*)(ws + 33554432);
    u64*   rT1 = (u64*)(ws + 33587200);
    int*   rdy = (int*)(ws + 33619968);
    float* tws = (float*)(ws + 33636352);
    float* pre = (float*)(ws + 50413568);
    const size_t NEED_TWS = 50413568ull;
    const size_t NEED_PRE = 67190784ull;
    const int use_tws = (ws_size >= NEED_TWS) ? 1 : 0;
    const int use_pre = (ws_size >= NEED_PRE) ? 1 : 0;

    hipMemsetAsync(rdy, 0, 16384, stream);
    swizzle_kernel<<<8192, 256, 0, stream>>>(W, Wsw);
    init_kernel<<<64, 256, 0, stream>>>(x0, (__hip_bfloat16*)rT0);
    if (use_pre)
        pre_kernel<<<TLEN, 256, 0, stream>>>(u, w_in_w, w_in_b, noise, pre);

    persist_kernel<<<256, 256, 0, stream>>>(
        Wsw, w_hh, u, w_in_w, w_in_b, noise, x0,
        rT0, rT1, traj, tws, xfinal, rdy, pre, use_pre, use_tws);

    if (use_tws)
        fixup_kernel<<<TLEN, 256, 0, stream>>>(tws, w_out_w, w_out_b, traj, xfinal, out);
    else
        output_kernel<<<(BSZ * TLEN) / 8, 256, 0, stream>>>(traj, w_out_w, w_out_b, out);
}